// Round 1
// baseline (174.794 us; speedup 1.0000x reference)
//
#include <hip/hip_runtime.h>
#include <hip/hip_bf16.h>
#include <stdint.h>

// Problem constants
// B=16, K=8, N=196, D=768, H=3072, DOUT=768
// y[b,n,:] = (mean_k relu(slots[b,k]@W1 + pos[n]@W1 + b1)) @ W2 + b2
// (softmax over K of K-identical values is exactly 1/K; map_alpha unused)

typedef __attribute__((ext_vector_type(8))) short bf16x8;
typedef __attribute__((ext_vector_type(4))) float f32x4;

static __device__ __forceinline__ unsigned short f2bf(float f) {
    union { float f; unsigned int u; } v; v.f = f;
    unsigned int u = v.u;
    return (unsigned short)((u + 0x7fffu + ((u >> 16) & 1u)) >> 16);  // RNE
}

// ---- W (Kd x Nd, f32 row-major) -> Wt (Nd x Kd, bf16 row-major) ----
__global__ void k_conv_transpose(const float* __restrict__ W,
                                 unsigned short* __restrict__ Wt,
                                 int Kd, int Nd) {
    int idx = blockIdx.x * blockDim.x + threadIdx.x;
    int total = Nd * (Kd / 8);
    if (idx >= total) return;
    int n  = idx % Nd;        // consecutive tid -> consecutive n -> coalesced reads
    int kb = idx / Nd;
    unsigned int po[4];
    #pragma unroll
    for (int j = 0; j < 4; ++j) {
        unsigned short lo = f2bf(W[(size_t)(kb * 8 + 2 * j) * Nd + n]);
        unsigned short hi = f2bf(W[(size_t)(kb * 8 + 2 * j + 1) * Nd + n]);
        po[j] = (unsigned int)lo | ((unsigned int)hi << 16);
    }
    uint4 out = make_uint4(po[0], po[1], po[2], po[3]);
    *(uint4*)(Wt + (size_t)n * Kd + kb * 8) = out;
}

// ---- pack A1 = concat(slots 128x768, pos_embed 196x768) as bf16 ----
__global__ void k_pack_rows(const float* __restrict__ S, const float* __restrict__ P,
                            unsigned short* __restrict__ A, int elemsS, int total8) {
    int idx = blockIdx.x * blockDim.x + threadIdx.x;
    if (idx >= total8) return;
    int base = idx * 8;
    const float* src = (base < elemsS) ? (S + base) : (P + (base - elemsS));
    float4 a = *(const float4*)(src);
    float4 b = *(const float4*)(src + 4);
    unsigned int po[4];
    po[0] = (unsigned int)f2bf(a.x) | ((unsigned int)f2bf(a.y) << 16);
    po[1] = (unsigned int)f2bf(a.z) | ((unsigned int)f2bf(a.w) << 16);
    po[2] = (unsigned int)f2bf(b.x) | ((unsigned int)f2bf(b.y) << 16);
    po[3] = (unsigned int)f2bf(b.z) | ((unsigned int)f2bf(b.w) << 16);
    *(uint4*)(A + base) = make_uint4(po[0], po[1], po[2], po[3]);
}

// ---- hbar[bn,h] = 0.125 * sum_k relu(s1[b*8+k,h] + p1[n,h] + b1[h]) -> bf16 ----
// C1: 324 x 3072 f32. rows 0..127 = s1 (b*8+k), rows 128..323 = p1 (n)
__global__ void k_hbar(const float* __restrict__ C1, const float* __restrict__ b1,
                       unsigned short* __restrict__ Hb) {
    int h = (blockIdx.x * blockDim.x + threadIdx.x) * 4;  // 3072/4=768 threads in x
    int bn = blockIdx.y;
    int b = bn / 196;
    int n = bn - b * 196;
    float4 p  = *(const float4*)(C1 + (size_t)(128 + n) * 3072 + h);
    float4 bb = *(const float4*)(b1 + h);
    p.x += bb.x; p.y += bb.y; p.z += bb.z; p.w += bb.w;
    float4 acc = make_float4(0.f, 0.f, 0.f, 0.f);
    #pragma unroll
    for (int k = 0; k < 8; ++k) {
        float4 s = *(const float4*)(C1 + (size_t)(b * 8 + k) * 3072 + h);
        acc.x += fmaxf(s.x + p.x, 0.f);
        acc.y += fmaxf(s.y + p.y, 0.f);
        acc.z += fmaxf(s.z + p.z, 0.f);
        acc.w += fmaxf(s.w + p.w, 0.f);
    }
    ushort4 o;
    o.x = f2bf(acc.x * 0.125f);
    o.y = f2bf(acc.y * 0.125f);
    o.z = f2bf(acc.z * 0.125f);
    o.w = f2bf(acc.w * 0.125f);
    *(ushort4*)(Hb + (size_t)bn * 3072 + h) = o;
}

// ---- bf16 MFMA GEMM: C(MxN) = A(MxK) @ B(KxN) + bias, B given transposed (NxK) ----
// 16x16x32 bf16 MFMA. A-frag: A[m=lane&15][k=(lane>>4)*8+j]; B-frag symmetric;
// C/D: col=lane&15, row=(lane>>4)*4+reg  [measured layouts, m89/m91]
template<int BM, int BN, int BK, int WM, int WN>
__launch_bounds__(256)
__global__ void gemm_bf16_tn(const unsigned short* __restrict__ A,   // M x K bf16
                             const unsigned short* __restrict__ Bt,  // N x K bf16
                             const float* __restrict__ bias,         // len N or null
                             float* __restrict__ C,                  // M x N f32
                             int M, int Nd, int Kd) {
    constexpr int PAD = 24;                 // stride 88 elems = 176B: 16B-aligned, 2-way banks
    constexpr int LDA = BK + PAD;
    constexpr int WAVES_N = BN / WN;
    constexpr int FM = WM / 16, FN = WN / 16;
    static_assert((BM / WM) * (BN / WN) == 4, "4 waves");

    __shared__ unsigned short As[BM * LDA];
    __shared__ unsigned short Bs[BN * LDA];

    const int tid  = threadIdx.x;
    const int lane = tid & 63;
    const int wave = tid >> 6;
    const int wm = wave / WAVES_N;
    const int wn = wave % WAVES_N;

    const int row0 = blockIdx.y * BM;
    const int col0 = blockIdx.x * BN;

    f32x4 acc[FM][FN] = {};

    constexpr int A_ITER = (BM * BK / 8) / 256;
    constexpr int B_ITER = (BN * BK / 8) / 256;

    for (int k0 = 0; k0 < Kd; k0 += BK) {
        __syncthreads();
        #pragma unroll
        for (int it = 0; it < A_ITER; ++it) {
            int c = it * 256 + tid;
            int r = c / (BK / 8);
            int kk = (c % (BK / 8)) * 8;
            int gr = row0 + r; if (gr >= M) gr = M - 1;   // clamp: garbage rows never stored
            uint4 v = *(const uint4*)(A + (size_t)gr * Kd + k0 + kk);
            *(uint4*)(&As[r * LDA + kk]) = v;
        }
        #pragma unroll
        for (int it = 0; it < B_ITER; ++it) {
            int c = it * 256 + tid;
            int r = c / (BK / 8);
            int kk = (c % (BK / 8)) * 8;
            uint4 v = *(const uint4*)(Bt + (size_t)(col0 + r) * Kd + k0 + kk);
            *(uint4*)(&Bs[r * LDA + kk]) = v;
        }
        __syncthreads();
        #pragma unroll
        for (int ks = 0; ks < BK / 32; ++ks) {
            const int kbase = ks * 32 + (lane >> 4) * 8;
            bf16x8 af[FM], bfr[FN];
            #pragma unroll
            for (int i = 0; i < FM; ++i) {
                int m = wm * WM + i * 16 + (lane & 15);
                af[i] = *(const bf16x8*)(&As[m * LDA + kbase]);
            }
            #pragma unroll
            for (int j = 0; j < FN; ++j) {
                int n = wn * WN + j * 16 + (lane & 15);
                bfr[j] = *(const bf16x8*)(&Bs[n * LDA + kbase]);
            }
            #pragma unroll
            for (int i = 0; i < FM; ++i)
                #pragma unroll
                for (int j = 0; j < FN; ++j)
                    acc[i][j] = __builtin_amdgcn_mfma_f32_16x16x32_bf16(af[i], bfr[j], acc[i][j], 0, 0, 0);
        }
    }

    #pragma unroll
    for (int i = 0; i < FM; ++i) {
        #pragma unroll
        for (int j = 0; j < FN; ++j) {
            int col = col0 + wn * WN + j * 16 + (lane & 15);
            float bv = bias ? bias[col] : 0.f;
            #pragma unroll
            for (int r = 0; r < 4; ++r) {
                int row = row0 + wm * WM + i * 16 + (lane >> 4) * 4 + r;
                if (row < M) C[(size_t)row * Nd + col] = acc[i][j][r] + bv;
            }
        }
    }
}

extern "C" void kernel_launch(void* const* d_in, const int* in_sizes, int n_in,
                              void* d_out, int out_size, void* d_ws, size_t ws_size,
                              hipStream_t stream) {
    const float* slots  = (const float*)d_in[0];   // 16*8*768
    const float* pos    = (const float*)d_in[1];   // 196*768
    // d_in[2] = map_alpha: mathematically unused (softmax of K-identical values = 1/K)
    const float* W1     = (const float*)d_in[3];   // 768*3072
    const float* b1     = (const float*)d_in[4];   // 3072
    const float* W2     = (const float*)d_in[5];   // 3072*768
    const float* b2     = (const float*)d_in[6];   // 768
    float* out = (float*)d_out;                    // 3136*768

    size_t off = 0;
    auto alloc = [&](size_t bytes) {
        void* p = (char*)d_ws + off;
        off += (bytes + 255) & ~(size_t)255;
        return p;
    };
    unsigned short* W1t = (unsigned short*)alloc((size_t)3072 * 768 * 2);  // 3072 x 768
    unsigned short* W2t = (unsigned short*)alloc((size_t)768 * 3072 * 2);  // 768 x 3072
    unsigned short* A1  = (unsigned short*)alloc((size_t)324 * 768 * 2);   // 324 x 768
    float*          C1  = (float*)alloc((size_t)324 * 3072 * 4);           // 324 x 3072
    unsigned short* Hb  = (unsigned short*)alloc((size_t)3136 * 3072 * 2); // 3136 x 3072

    // 1) weight converts (transposed, bf16)
    k_conv_transpose<<<(3072 * (768 / 8) + 255) / 256, 256, 0, stream>>>(W1, W1t, 768, 3072);
    k_conv_transpose<<<(768 * (3072 / 8) + 255) / 256, 256, 0, stream>>>(W2, W2t, 3072, 768);
    // 2) pack A1 = [slots; pos_embed] bf16
    k_pack_rows<<<((324 * 768 / 8) + 255) / 256, 256, 0, stream>>>(slots, pos, A1, 128 * 768, 324 * 768 / 8);
    // 3) C1 = A1 @ W1  (324 x 3072, K=768)
    gemm_bf16_tn<64, 64, 64, 32, 32><<<dim3(3072 / 64, (324 + 63) / 64), 256, 0, stream>>>(
        A1, W1t, nullptr, C1, 324, 3072, 768);
    // 4) hbar = mean_k relu(s1 + p1 + b1) -> bf16
    k_hbar<<<dim3(3, 3136), 256, 0, stream>>>(C1, b1, Hb);
    // 5) out = hbar @ W2 + b2  (3136 x 768, K=3072)
    gemm_bf16_tn<128, 64, 64, 64, 32><<<dim3(768 / 64, (3136 + 127) / 128), 256, 0, stream>>>(
        Hb, W2t, b2, out, 3136, 768, 3072);
}

// Round 2
// 166.187 us; speedup vs baseline: 1.0518x; 1.0518x over previous
//
#include <hip/hip_runtime.h>
#include <hip/hip_bf16.h>
#include <stdint.h>

// B=16, K=8, N=196, D=768, H=3072, DOUT=768
// y[b,n,:] = (mean_k relu(slots[b,k]@W1 + pos[n]@W1 + b1)) @ W2 + b2
// (softmax over K of K-identical values is exactly 1/K; map_alpha unused)

typedef __attribute__((ext_vector_type(8))) short bf16x8;
typedef __attribute__((ext_vector_type(4))) float f32x4;

#define AS1 __attribute__((address_space(1)))
#define AS3 __attribute__((address_space(3)))

static __device__ __forceinline__ void gld_lds16(const void* g, void* l) {
    // async global->LDS, 16B per lane; LDS dst must be wave-uniform base + lane*16
    __builtin_amdgcn_global_load_lds((const AS1 unsigned int*)g,
                                     (AS3 unsigned int*)l, 16, 0, 0);
}

static __device__ __forceinline__ unsigned short f2bf(float f) {
    union { float f; unsigned int u; } v; v.f = f;
    unsigned int u = v.u;
    return (unsigned short)((u + 0x7fffu + ((u >> 16) & 1u)) >> 16);  // RNE
}

// ---------------- fused prep: W1 transpose, W2 transpose, A1 pack ----------------
static __device__ __forceinline__ void conv_t(const float* __restrict__ W,
                                              unsigned short* __restrict__ Wt,
                                              int Kd, int Nd, int idx) {
    int n  = idx % Nd;        // consecutive tid -> consecutive n -> coalesced reads
    int kb = idx / Nd;
    unsigned int po[4];
    #pragma unroll
    for (int j = 0; j < 4; ++j) {
        unsigned short lo = f2bf(W[(size_t)(kb * 8 + 2 * j) * Nd + n]);
        unsigned short hi = f2bf(W[(size_t)(kb * 8 + 2 * j + 1) * Nd + n]);
        po[j] = (unsigned int)lo | ((unsigned int)hi << 16);
    }
    *(uint4*)(Wt + (size_t)n * Kd + kb * 8) = make_uint4(po[0], po[1], po[2], po[3]);
}

__global__ void k_prep(const float* __restrict__ W1, unsigned short* __restrict__ W1t,
                       const float* __restrict__ W2, unsigned short* __restrict__ W2t,
                       const float* __restrict__ S, const float* __restrict__ P,
                       unsigned short* __restrict__ A1) {
    int idx = blockIdx.x * blockDim.x + threadIdx.x;
    const int C1n = 3072 * (768 / 8);       // 294912 W1t chunks
    const int C2n = 768 * (3072 / 8);       // 294912 W2t chunks
    const int PKn = 324 * 768 / 8;          // 31104 pack chunks
    if (idx < C1n) {
        conv_t(W1, W1t, 768, 3072, idx);
    } else if (idx < C1n + C2n) {
        conv_t(W2, W2t, 3072, 768, idx - C1n);
    } else if (idx < C1n + C2n + PKn) {
        int base = (idx - C1n - C2n) * 8;
        const int elemsS = 128 * 768;
        const float* src = (base < elemsS) ? (S + base) : (P + (base - elemsS));
        float4 a = *(const float4*)(src);
        float4 b = *(const float4*)(src + 4);
        unsigned int po[4];
        po[0] = (unsigned int)f2bf(a.x) | ((unsigned int)f2bf(a.y) << 16);
        po[1] = (unsigned int)f2bf(a.z) | ((unsigned int)f2bf(a.w) << 16);
        po[2] = (unsigned int)f2bf(b.x) | ((unsigned int)f2bf(b.y) << 16);
        po[3] = (unsigned int)f2bf(b.z) | ((unsigned int)f2bf(b.w) << 16);
        *(uint4*)(A1 + base) = make_uint4(po[0], po[1], po[2], po[3]);
    }
}

// ---- hbar[bn,h] = 0.125 * sum_k relu(s1[b*8+k,h] + p1[n,h] + b1[h]) -> bf16 ----
// C1: 324 x 3072 f32; rows 0..127 = s1 (b*8+k), rows 128..323 = p1 (n)
// Block = (hc in 0..2, ng in 0..6, b in 0..15); registers cache the 8 s-rows.
__global__ void k_hbar(const float* __restrict__ C1, const float* __restrict__ b1,
                       unsigned short* __restrict__ Hb) {
    const int h  = blockIdx.x * 1024 + threadIdx.x * 4;
    const int b  = blockIdx.z;
    const int n0 = blockIdx.y * 28;
    float4 bb = *(const float4*)(b1 + h);
    float4 t[8];
    #pragma unroll
    for (int k = 0; k < 8; ++k) {
        float4 s = *(const float4*)(C1 + (size_t)(b * 8 + k) * 3072 + h);
        t[k] = make_float4(s.x + bb.x, s.y + bb.y, s.z + bb.z, s.w + bb.w);
    }
    for (int n = n0; n < n0 + 28; ++n) {
        float4 p = *(const float4*)(C1 + (size_t)(128 + n) * 3072 + h);
        float4 acc = make_float4(0.f, 0.f, 0.f, 0.f);
        #pragma unroll
        for (int k = 0; k < 8; ++k) {
            acc.x += fmaxf(t[k].x + p.x, 0.f);
            acc.y += fmaxf(t[k].y + p.y, 0.f);
            acc.z += fmaxf(t[k].z + p.z, 0.f);
            acc.w += fmaxf(t[k].w + p.w, 0.f);
        }
        ushort4 o;
        o.x = f2bf(acc.x * 0.125f);
        o.y = f2bf(acc.y * 0.125f);
        o.z = f2bf(acc.z * 0.125f);
        o.w = f2bf(acc.w * 0.125f);
        *(ushort4*)(Hb + (size_t)(b * 196 + n) * 3072 + h) = o;
    }
}

// ---- bf16 MFMA GEMM, m97-style: global_load_lds staging, unpadded LDS ----
// C(MxN) = A(MxK) @ Bt(NxK)^T + bias. 16x16x32 bf16 MFMA.
// A-frag: A[m=lane&15][k=(lane>>4)*8+j]; B-frag symmetric;
// C/D: col=lane&15, row=(lane>>4)*4+reg  [measured m89/m91]
template<int BM, int BN, int BK, int WM, int WN>
__launch_bounds__(256)
__global__ void gemm_async(const unsigned short* __restrict__ A,   // M x K bf16
                           const unsigned short* __restrict__ Bt,  // N x K bf16
                           const float* __restrict__ bias,         // len N or null
                           float* __restrict__ C,                  // M x N f32
                           int M, int Nd, int Kd) {
    constexpr int FM = WM / 16, FN = WN / 16;
    constexpr int WAVES_N = BN / WN;
    static_assert((BM / WM) * (BN / WN) == 4, "4 waves");
    // Unpadded: required by global_load_lds (dst = wave base + lane*16)
    __shared__ unsigned short As[BM * BK];
    __shared__ unsigned short Bs[BN * BK];

    const int tid  = threadIdx.x;
    const int lane = tid & 63;
    const int wave = tid >> 6;
    const int wm = wave / WAVES_N;
    const int wn = wave % WAVES_N;
    const int row0 = blockIdx.y * BM;
    const int col0 = blockIdx.x * BN;

    f32x4 acc[FM][FN] = {};

    constexpr int ACH = (BM * BK) / (8 * 256);   // 16B chunks per thread
    constexpr int BCH = (BN * BK) / (8 * 256);

    for (int k0 = 0; k0 < Kd; k0 += BK) {
        __syncthreads();
        #pragma unroll
        for (int it = 0; it < ACH; ++it) {
            int c = it * 256 + tid;
            int r = c / (BK / 8);
            int kk = (c % (BK / 8)) * 8;
            int gr = row0 + r; if (gr >= M) gr = M - 1;   // clamped rows never stored
            gld_lds16(A + (size_t)gr * Kd + k0 + kk, &As[c * 8]);
        }
        #pragma unroll
        for (int it = 0; it < BCH; ++it) {
            int c = it * 256 + tid;
            int r = c / (BK / 8);
            int kk = (c % (BK / 8)) * 8;
            gld_lds16(Bt + (size_t)(col0 + r) * Kd + k0 + kk, &Bs[c * 8]);
        }
        __syncthreads();   // compiler inserts s_waitcnt vmcnt(0) before s_barrier
        #pragma unroll
        for (int ks = 0; ks < BK / 32; ++ks) {
            const int kbase = ks * 32 + (lane >> 4) * 8;
            bf16x8 af[FM], bfr[FN];
            #pragma unroll
            for (int i = 0; i < FM; ++i) {
                int m = wm * WM + i * 16 + (lane & 15);
                af[i] = *(const bf16x8*)(&As[m * BK + kbase]);
            }
            #pragma unroll
            for (int j = 0; j < FN; ++j) {
                int n = wn * WN + j * 16 + (lane & 15);
                bfr[j] = *(const bf16x8*)(&Bs[n * BK + kbase]);
            }
            #pragma unroll
            for (int i = 0; i < FM; ++i)
                #pragma unroll
                for (int j = 0; j < FN; ++j)
                    acc[i][j] = __builtin_amdgcn_mfma_f32_16x16x32_bf16(af[i], bfr[j], acc[i][j], 0, 0, 0);
        }
    }

    #pragma unroll
    for (int i = 0; i < FM; ++i) {
        #pragma unroll
        for (int j = 0; j < FN; ++j) {
            int col = col0 + wn * WN + j * 16 + (lane & 15);
            float bv = bias ? bias[col] : 0.f;
            #pragma unroll
            for (int r = 0; r < 4; ++r) {
                int row = row0 + wm * WM + i * 16 + (lane >> 4) * 4 + r;
                if (row < M) C[(size_t)row * Nd + col] = acc[i][j][r] + bv;
            }
        }
    }
}

extern "C" void kernel_launch(void* const* d_in, const int* in_sizes, int n_in,
                              void* d_out, int out_size, void* d_ws, size_t ws_size,
                              hipStream_t stream) {
    const float* slots  = (const float*)d_in[0];   // 16*8*768
    const float* pos    = (const float*)d_in[1];   // 196*768
    // d_in[2] = map_alpha: unused (softmax over K of identical values = 1/K)
    const float* W1     = (const float*)d_in[3];   // 768*3072
    const float* b1     = (const float*)d_in[4];   // 3072
    const float* W2     = (const float*)d_in[5];   // 3072*768
    const float* b2     = (const float*)d_in[6];   // 768
    float* out = (float*)d_out;                    // 3136*768 f32

    size_t off = 0;
    auto alloc = [&](size_t bytes) {
        void* p = (char*)d_ws + off;
        off += (bytes + 255) & ~(size_t)255;
        return p;
    };
    unsigned short* W1t = (unsigned short*)alloc((size_t)3072 * 768 * 2);  // 3072 x 768
    unsigned short* W2t = (unsigned short*)alloc((size_t)768 * 3072 * 2);  // 768 x 3072
    unsigned short* A1  = (unsigned short*)alloc((size_t)324 * 768 * 2);   // 324 x 768
    float*          C1  = (float*)alloc((size_t)324 * 3072 * 4);           // 324 x 3072
    unsigned short* Hb  = (unsigned short*)alloc((size_t)3136 * 3072 * 2); // 3136 x 3072

    // 1) fused prep: both weight transposes + A1 pack (1 dispatch)
    const int total = 294912 + 294912 + 31104;
    k_prep<<<(total + 255) / 256, 256, 0, stream>>>(W1, W1t, W2, W2t, slots, pos, A1);
    // 2) C1 = A1 @ W1  (324 x 3072, K=768) — 288 blocks
    gemm_async<64, 64, 64, 32, 32><<<dim3(3072 / 64, (324 + 63) / 64), 256, 0, stream>>>(
        A1, W1t, nullptr, C1, 324, 3072, 768);
    // 3) hbar = mean_k relu(s1 + p1 + b1) -> bf16 (336 blocks, s-rows in regs)
    k_hbar<<<dim3(3, 7, 16), 256, 0, stream>>>(C1, b1, Hb);
    // 4) out = hbar @ W2 + b2  (3136 x 768, K=3072) — 588 blocks for occupancy
    gemm_async<64, 64, 64, 32, 32><<<dim3(768 / 64, 3136 / 64), 256, 0, stream>>>(
        Hb, W2t, b2, out, 3136, 768, 3072);
}

// Round 3
// 138.492 us; speedup vs baseline: 1.2621x; 1.2000x over previous
//
#include <hip/hip_runtime.h>
#include <hip/hip_bf16.h>
#include <stdint.h>

// B=16, K=8, N=196, D=768, H=3072, DOUT=768
// y[b,n,:] = (mean_k relu(slots[b,k]@W1 + pos[n]@W1 + b1)) @ W2 + b2
// (softmax over K of K-identical values is exactly 1/K; map_alpha unused)
//
// All GEMM operands live in ws pre-tiled to the exact LDS image:
//   64x64 tile, chunk index cw = kb*64 + r (kb=k/8 within tile, r=row within
//   tile), element offset = tile_base + cw*8.  Staging is then a pure linear
//   global_load_lds stream AND fragment ds_read_b128s are consecutive-16B
//   within each 16-lane group (conflict-free).

typedef __attribute__((ext_vector_type(8))) short bf16x8;
typedef __attribute__((ext_vector_type(4))) float f32x4;

#define AS1 __attribute__((address_space(1)))
#define AS3 __attribute__((address_space(3)))

#define WAIT_VM(N) asm volatile("s_waitcnt vmcnt(" #N ")" ::: "memory")
#define BAR()      asm volatile("s_barrier" ::: "memory")
#define BAR_LDS()  asm volatile("s_waitcnt lgkmcnt(0)\ns_barrier" ::: "memory")

static __device__ __forceinline__ void gld_lds16(const void* g, void* l) {
    __builtin_amdgcn_global_load_lds((const AS1 unsigned int*)g,
                                     (AS3 unsigned int*)l, 16, 0, 0);
}

static __device__ __forceinline__ unsigned short f2bf(float f) {
    union { float f; unsigned int u; } v; v.f = f;
    unsigned int u = v.u;
    return (unsigned short)((u + 0x7fffu + ((u >> 16) & 1u)) >> 16);  // RNE
}

// ---------------- prep: W1t / W2t tiled transposes + A1 tiled pack ----------------
// W (Kd x Rd f32 row-major) -> Wt tiled (Rd rows, Kd k): task = (kc, r)
static __device__ __forceinline__ void conv_tiled(const float* __restrict__ W,
                                                  unsigned short* __restrict__ Wt,
                                                  int Kd, int Rd, int idx) {
    int r  = idx % Rd;                 // consecutive tid -> consecutive r
    int kc = idx / Rd;                 // k-chunk (8 elems)
    unsigned int po[4];
    #pragma unroll
    for (int j = 0; j < 4; ++j) {
        unsigned short lo = f2bf(W[(size_t)(kc * 8 + 2 * j) * Rd + r]);
        unsigned short hi = f2bf(W[(size_t)(kc * 8 + 2 * j + 1) * Rd + r]);
        po[j] = (unsigned int)lo | ((unsigned int)hi << 16);
    }
    size_t dst = ((size_t)(r >> 6) * (Kd >> 6) + (kc >> 3)) * 4096
               + (size_t)((kc & 7) * 64 + (r & 63)) * 8;
    *(uint4*)(Wt + dst) = make_uint4(po[0], po[1], po[2], po[3]);  // coalesced
}

__global__ void k_prep(const float* __restrict__ W1, unsigned short* __restrict__ W1t,
                       const float* __restrict__ W2, unsigned short* __restrict__ W2t,
                       const float* __restrict__ S, const float* __restrict__ P,
                       unsigned short* __restrict__ A1) {
    int idx = blockIdx.x * blockDim.x + threadIdx.x;
    const int C1n = 96 * 3072;          // W1t tasks (Kd=768 -> 96 kc, Rd=3072)
    const int C2n = 384 * 768;          // W2t tasks (Kd=3072 -> 384 kc, Rd=768)
    const int PKn = 96 * 384;           // A1 tasks (Kd=768, 384 padded rows)
    if (idx < C1n) {
        conv_tiled(W1, W1t, 768, 3072, idx);
    } else if (idx < C1n + C2n) {
        conv_tiled(W2, W2t, 3072, 768, idx - C1n);
    } else if (idx < C1n + C2n + PKn) {
        int t = idx - C1n - C2n;
        int r  = t % 384;               // consecutive tid -> consecutive r (coalesced write)
        int kc = t / 384;
        uint4 o = make_uint4(0u, 0u, 0u, 0u);
        if (r < 324) {
            const float* src = (r < 128) ? (S + (size_t)r * 768 + kc * 8)
                                         : (P + (size_t)(r - 128) * 768 + kc * 8);
            float4 a = *(const float4*)(src);
            float4 b = *(const float4*)(src + 4);
            o.x = (unsigned int)f2bf(a.x) | ((unsigned int)f2bf(a.y) << 16);
            o.y = (unsigned int)f2bf(a.z) | ((unsigned int)f2bf(a.w) << 16);
            o.z = (unsigned int)f2bf(b.x) | ((unsigned int)f2bf(b.y) << 16);
            o.w = (unsigned int)f2bf(b.z) | ((unsigned int)f2bf(b.w) << 16);
        }
        size_t dst = ((size_t)(r >> 6) * 12 + (kc >> 3)) * 4096
                   + (size_t)((kc & 7) * 64 + (r & 63)) * 8;
        *(uint4*)(A1 + dst) = o;
    }
}

// ---- hbar: one wave = 64 consecutive bn x 8 h; writes GEMM2's tiled A layout ----
// C1 (f32, 384x3072 row-major; rows 0..127 s1[b*8+k], 128..323 p1[n])
__global__ void k_hbar(const float* __restrict__ C1, const float* __restrict__ b1,
                       unsigned short* __restrict__ Hb) {
    const int lane = threadIdx.x & 63;
    const int wv   = threadIdx.x >> 6;
    const int hc   = blockIdx.y * 4 + wv;          // 0..383
    const int h0   = hc * 8;
    const int bn   = blockIdx.x * 64 + lane;       // 0..3135
    const int b    = bn / 196;
    const int n    = bn - b * 196;
    const float* prow = C1 + (size_t)(128 + n) * 3072 + h0;
    float4 pA = *(const float4*)(prow);
    float4 pB = *(const float4*)(prow + 4);
    float4 bA = *(const float4*)(b1 + h0);
    float4 bB = *(const float4*)(b1 + h0 + 4);
    float pb[8] = { pA.x + bA.x, pA.y + bA.y, pA.z + bA.z, pA.w + bA.w,
                    pB.x + bB.x, pB.y + bB.y, pB.z + bB.z, pB.w + bB.w };
    float acc[8] = {};
    #pragma unroll
    for (int k = 0; k < 8; ++k) {
        const float* srow = C1 + (size_t)(b * 8 + k) * 3072 + h0;  // broadcast-ish
        float4 sA_ = *(const float4*)(srow);
        float4 sB_ = *(const float4*)(srow + 4);
        acc[0] += fmaxf(sA_.x + pb[0], 0.f);
        acc[1] += fmaxf(sA_.y + pb[1], 0.f);
        acc[2] += fmaxf(sA_.z + pb[2], 0.f);
        acc[3] += fmaxf(sA_.w + pb[3], 0.f);
        acc[4] += fmaxf(sB_.x + pb[4], 0.f);
        acc[5] += fmaxf(sB_.y + pb[5], 0.f);
        acc[6] += fmaxf(sB_.z + pb[6], 0.f);
        acc[7] += fmaxf(sB_.w + pb[7], 0.f);
    }
    unsigned int w0 = (unsigned int)f2bf(acc[0] * 0.125f) | ((unsigned int)f2bf(acc[1] * 0.125f) << 16);
    unsigned int w1 = (unsigned int)f2bf(acc[2] * 0.125f) | ((unsigned int)f2bf(acc[3] * 0.125f) << 16);
    unsigned int w2 = (unsigned int)f2bf(acc[4] * 0.125f) | ((unsigned int)f2bf(acc[5] * 0.125f) << 16);
    unsigned int w3 = (unsigned int)f2bf(acc[6] * 0.125f) | ((unsigned int)f2bf(acc[7] * 0.125f) << 16);
    // tiled A layout for GEMM2: rt=blockIdx.x, kt=hc>>3, kb=hc&7, r=lane
    size_t dst = ((size_t)blockIdx.x * 48 + (hc >> 3)) * 4096
               + (size_t)((hc & 7) * 64 + lane) * 8;
    *(uint4*)(Hb + dst) = make_uint4(w0, w1, w2, w3);              // coalesced 16B/lane
}

// ---- tiled bf16 MFMA GEMM, double-buffered, raw-barrier pipeline ----
// A: tiled (Mtiles x KT x 4096), Bt: tiled (Ntiles x KT x 4096)
// C: M x Nd f32 row-major (+bias). 16x16x32 bf16 MFMA; BM=BN=BK=64, 4 waves.
__launch_bounds__(256)
__global__ void gemm_tiled(const unsigned short* __restrict__ A,
                           const unsigned short* __restrict__ Bt,
                           const float* __restrict__ bias,
                           float* __restrict__ C,
                           int Mstore, int Nd, int KT) {
    __shared__ unsigned short smem[2 * 8192];   // [buf][A 4096 | B 4096]

    const int tid  = threadIdx.x;
    const int lane = tid & 63;
    const int wave = tid >> 6;
    const int wm   = wave >> 1;
    const int wn   = wave & 1;
    const int q    = lane >> 4;
    const int l16  = lane & 15;

    const unsigned short* Abase = A  + (size_t)blockIdx.y * KT * 4096;
    const unsigned short* Bbase = Bt + (size_t)blockIdx.x * KT * 4096;

    f32x4 acc[2][2] = {};

    // LDS chunk offsets for this thread's fragments (elements)
    const int offA0 = ((q * 64) + wm * 32 + l16) * 8;        // + ks*4*64*8 per ks
    const int offB0 = ((q * 64) + wn * 32 + l16) * 8;

    // initial stage -> buf0
    {
        #pragma unroll
        for (int it = 0; it < 2; ++it) {
            int c = it * 256 + tid;
            gld_lds16(Abase + (size_t)c * 8, smem + c * 8);
        }
        #pragma unroll
        for (int it = 0; it < 2; ++it) {
            int c = it * 256 + tid;
            gld_lds16(Bbase + (size_t)c * 8, smem + 4096 + c * 8);
        }
    }

    auto step = [&](const unsigned short* sA, const unsigned short* sB,
                    unsigned short* dA, unsigned short* dB, int i) {
        const bool pf = (i + 1 < KT);
        if (pf) {
            const unsigned short* Ag = Abase + (size_t)(i + 1) * 4096;
            const unsigned short* Bg = Bbase + (size_t)(i + 1) * 4096;
            #pragma unroll
            for (int it = 0; it < 2; ++it) {
                int c = it * 256 + tid;
                gld_lds16(Ag + (size_t)c * 8, dA + c * 8);
            }
            #pragma unroll
            for (int it = 0; it < 2; ++it) {
                int c = it * 256 + tid;
                gld_lds16(Bg + (size_t)c * 8, dB + c * 8);
            }
            WAIT_VM(4);       // previous tile's 4 loads retired; prefetch in flight
        } else {
            WAIT_VM(0);
        }
        BAR();
        #pragma unroll
        for (int ks = 0; ks < 2; ++ks) {
            const int ko = ks * 4 * 64 * 8;
            bf16x8 af[2], bfr[2];
            af[0]  = *(const bf16x8*)(sA + offA0 + ko);
            af[1]  = *(const bf16x8*)(sA + offA0 + ko + 16 * 8);
            bfr[0] = *(const bf16x8*)(sB + offB0 + ko);
            bfr[1] = *(const bf16x8*)(sB + offB0 + ko + 16 * 8);
            #pragma unroll
            for (int ii = 0; ii < 2; ++ii)
                #pragma unroll
                for (int jj = 0; jj < 2; ++jj)
                    acc[ii][jj] = __builtin_amdgcn_mfma_f32_16x16x32_bf16(
                        af[ii], bfr[jj], acc[ii][jj], 0, 0, 0);
        }
        if (pf) BAR_LDS();   // all waves done reading this buf before next overwrite
    };

    for (int i = 0; i < KT; i += 2) {            // KT is even (12 or 48)
        step(smem,        smem + 4096, smem + 8192, smem + 12288, i);
        step(smem + 8192, smem + 12288, smem,       smem + 4096,  i + 1);
    }

    // epilogue: C/D layout col=lane&15, row=(lane>>4)*4+reg
    const int row0 = blockIdx.y * 64 + wm * 32;
    const int col0 = blockIdx.x * 64 + wn * 32;
    #pragma unroll
    for (int ii = 0; ii < 2; ++ii) {
        #pragma unroll
        for (int jj = 0; jj < 2; ++jj) {
            int col = col0 + jj * 16 + l16;
            float bv = bias ? bias[col] : 0.f;
            #pragma unroll
            for (int r = 0; r < 4; ++r) {
                int row = row0 + ii * 16 + q * 4 + r;
                if (row < Mstore) C[(size_t)row * Nd + col] = acc[ii][jj][r] + bv;
            }
        }
    }
}

extern "C" void kernel_launch(void* const* d_in, const int* in_sizes, int n_in,
                              void* d_out, int out_size, void* d_ws, size_t ws_size,
                              hipStream_t stream) {
    const float* slots  = (const float*)d_in[0];   // 16*8*768
    const float* pos    = (const float*)d_in[1];   // 196*768
    // d_in[2] = map_alpha: unused (softmax over K of identical values = 1/K)
    const float* W1     = (const float*)d_in[3];   // 768*3072
    const float* b1     = (const float*)d_in[4];   // 3072
    const float* W2     = (const float*)d_in[5];   // 3072*768
    const float* b2     = (const float*)d_in[6];   // 768
    float* out = (float*)d_out;                    // 3136*768 f32

    size_t off = 0;
    auto alloc = [&](size_t bytes) {
        void* p = (char*)d_ws + off;
        off += (bytes + 255) & ~(size_t)255;
        return p;
    };
    unsigned short* W1t = (unsigned short*)alloc((size_t)3072 * 768 * 2);   // tiled 48x12
    unsigned short* W2t = (unsigned short*)alloc((size_t)768 * 3072 * 2);   // tiled 12x48
    unsigned short* A1  = (unsigned short*)alloc((size_t)384 * 768 * 2);    // tiled 6x12
    float*          C1  = (float*)alloc((size_t)324 * 3072 * 4);            // row-major
    unsigned short* Hb  = (unsigned short*)alloc((size_t)3136 * 3072 * 2);  // tiled 49x48

    // 1) prep: tiled weight transposes + tiled A1 pack
    const int total = 96 * 3072 + 384 * 768 + 96 * 384;
    k_prep<<<(total + 255) / 256, 256, 0, stream>>>(W1, W1t, W2, W2t, slots, pos, A1);
    // 2) C1 = A1 @ W1t^T  (324x3072, K=768) — 288 blocks, KT=12
    gemm_tiled<<<dim3(48, 6), 256, 0, stream>>>(A1, W1t, nullptr, C1, 324, 3072, 12);
    // 3) hbar -> Hb in GEMM2-tiled layout — 4704 blocks
    k_hbar<<<dim3(49, 96), 256, 0, stream>>>(C1, b1, Hb);
    // 4) out = Hb @ W2t^T + b2  (3136x768, K=3072) — 588 blocks, KT=48
    gemm_tiled<<<dim3(12, 49), 256, 0, stream>>>(Hb, W2t, b2, out, 3136, 768, 48);
}